// Round 14
// baseline (165.638 us; speedup 1.0000x reference)
//
#include <hip/hip_runtime.h>
#include <hip/hip_bf16.h>

// Problem constants
#define NB 256
#define NACT 21
#define NA 8192
#define NE 262144
#define CSR_CAP 128
#define LOG2E 1.44269504f

#if __has_builtin(__builtin_amdgcn_exp2f)
#define EXP2F(x) __builtin_amdgcn_exp2f(x)
#else
#define EXP2F(x) exp2f(x)
#endif

typedef __attribute__((ext_vector_type(8))) short short8;
typedef __attribute__((ext_vector_type(4))) float float4v;

__device__ inline float wsum64(float v) {
#pragma unroll
  for (int m = 32; m > 0; m >>= 1) v += __shfl_xor(v, m, 64);
  return v;
}

__device__ inline unsigned short f2bf(float f) {
  union { __hip_bfloat16 h; unsigned short u; } cv;
  cv.h = __float2bfloat16(f);
  return cv.u;
}

// ---------------- K_A: conv1+conv2 per image (0..255) | cnt zero (256..271)
// ----------------      | prep fcw/w2t/wpart (272..783)  -- all independent ----------------
// conv block: conv1 -> c1s (LDS) -> im2col bf16 (LDS) -> conv2 via MFMA (4 waves) -> h1024bf.
// (512,4): ~44 VGPR class, 23 KB LDS -> 4 blocks/CU for latency hiding.
__global__ __launch_bounds__(512, 4) void k_ip(
    const float* __restrict__ x, const float* __restrict__ c1w, const float* __restrict__ c1b_,
    const float* __restrict__ c2w, const float* __restrict__ c2b, const float* __restrict__ fcw,
    const float* __restrict__ g2w, const float* __restrict__ g2b,
    unsigned short* h1024bf, int* cnt,
    unsigned short* fcwbf, unsigned short* w2t, float* wpart) {
  __shared__ __align__(16) float sm[5744];  // conv: xs[845] w1s[1440] c1s[1152] | c1bf@3440 (2304f=4608ush)
  int t = threadIdx.x, b = blockIdx.x;
  int wave = t >> 6, lane = t & 63;
  if (b >= 272) {  // ---- prep: fcw->bf16, W2 transpose + partials ----
    float (*red)[17] = (float(*)[17])sm;
    float* b2s = sm + 272;
    int blk = b - 272;
    {  // fcw -> bf16: 2 floats per thread
      int base = (blk * 512 + t) * 2;
      float2 v = *(const float2*)&fcw[base];
      fcwbf[base + 0] = f2bf(v.x);
      fcwbf[base + 1] = f2bf(v.y);
    }
    {  // W2: block owns 16 cols; w2t[j][k] = W2[k][j] bf16; column partial sums
      if (t < 256) {
        int jj = t >> 4, k = t & 15;
        int j = blk * 16 + jj;
        float w = g2w[k * 8192 + j];
        w2t[j * 16 + k] = f2bf(w);
        red[jj][k] = w;
      }
      if (t < 16) b2s[t] = g2b[blk * 16 + t];
      __syncthreads();
      if (t < 16) {
        float s = 0.0f;
#pragma unroll
        for (int q = 0; q < 16; q++) s += red[q][t];
        wpart[blk * 17 + t] = s;
      } else if (t == 16) {
        float s = 0.0f;
#pragma unroll
        for (int q = 0; q < 16; q++) s += b2s[q];
        wpart[blk * 17 + 16] = s;
      }
    }
    return;
  }
  if (b >= 256) {  // zero cnt
    cnt[(b - 256) * 512 + t] = 0;
    return;
  }
  // ---- conv1 for image b ----
  float* xs = sm;
  float* w1s = sm + 845;
  float* c1s = sm + 2285;
  unsigned short* c1bf = (unsigned short*)(sm + 3440);  // [16 pos][288 k] bf16, 16B-aligned rows
  for (int i = t; i < 845; i += 512) xs[i] = x[b * 845 + i];
  for (int i = t; i < 1440; i += 512) w1s[i] = c1w[i];
  __syncthreads();
  for (int idx = t; idx < 1152; idx += 512) {
    int oc = idx / 36, p = idx - oc * 36;
    int oy = p / 6, ox = p - oy * 6;
    float acc = c1b_[oc];
    const float* wp = &w1s[oc * 45];
#pragma unroll
    for (int ic = 0; ic < 5; ic++)
#pragma unroll
      for (int ky = 0; ky < 3; ky++)
#pragma unroll
        for (int kx = 0; kx < 3; kx++)
          acc += xs[ic * 169 + (oy * 2 + ky) * 13 + ox * 2 + kx] * wp[ic * 9 + ky * 3 + kx];
    c1s[idx] = fmaxf(acc, 0.0f);
  }
  __syncthreads();
  // ---- im2col to LDS (bf16): c1bf[p*288 + k] ----
  for (int i = t; i < 4608; i += 512) {
    int p = i / 288, k = i - p * 288;
    int ic = k / 9, rr = k - ic * 9;
    int ky = rr / 3, kx = rr - ky * 3;
    int oy = p >> 2, ox = p & 3;
    c1bf[i] = f2bf(c1s[ic * 36 + (oy + ky) * 6 + ox + kx]);
  }
  __syncthreads();
  // ---- conv2 GEMM: M=64(oc) x K=288 x N=16(pos); wave w owns ocs w*16..+16 ----
  if (wave < 4) {
    int m = lane & 15, quad = lane >> 4;
    float4v acc = {0.0f, 0.0f, 0.0f, 0.0f};
#pragma unroll
    for (int ks = 0; ks < 9; ks++) {
      int ko = ks * 32 + quad * 8;
      const float* ar = &c2w[(wave * 16 + m) * 288 + ko];  // convert A on the fly (== old w2abf)
      float4 af0 = *(const float4*)ar;
      float4 af1 = *(const float4*)(ar + 4);
      short8 a;
      a[0] = (short)f2bf(af0.x); a[1] = (short)f2bf(af0.y);
      a[2] = (short)f2bf(af0.z); a[3] = (short)f2bf(af0.w);
      a[4] = (short)f2bf(af1.x); a[5] = (short)f2bf(af1.y);
      a[6] = (short)f2bf(af1.z); a[7] = (short)f2bf(af1.w);
      short8 bv = *(const short8*)&c1bf[m * 288 + ko];
      acc = __builtin_amdgcn_mfma_f32_16x16x32_bf16(a, bv, acc, 0, 0, 0);
    }
#pragma unroll
    for (int r = 0; r < 4; r++) {
      int oc = wave * 16 + quad * 4 + r;  // D row = oc (A side); D col = m = pos (B side)
      h1024bf[b * 1024 + oc * 16 + m] = f2bf(fmaxf(acc[r] + c2b[oc], 0.0f));
    }
  }
}

// ---------------- K_B: FC tiles (0..511) | CSR (512..1023) | wsf (1024) ----------------
__global__ __launch_bounds__(512, 4) void k_cf(
    const int* __restrict__ edges, int* cnt, int* csr,
    const unsigned short* __restrict__ h1024bf, const unsigned short* __restrict__ fcwbf,
    const float* __restrict__ fcb, const float* __restrict__ wpart,
    float* hidden, float* wsf) {
  __shared__ float red[2048];  // [8][256] fc reduce / wsf parts
  int t = threadIdx.x, blk = blockIdx.x;
  int wave = t >> 6, lane = t & 63;
  int m = lane & 15, quad = lane >> 4;
  if (blk >= 1024) {  // ---- wsf reduce ----
    if (t < 272) {
      int q = t / 17, c = t - q * 17;
      float s = 0.0f;
      for (int r = q; r < 512; r += 16) s += wpart[r * 17 + c];
      red[t] = s;
    }
    __syncthreads();
    if (t < 17) {
      float s = 0.0f;
#pragma unroll
      for (int q = 0; q < 16; q++) s += red[q * 17 + t];
      wsf[t] = s;
    }
    return;
  }
  if (blk >= 512) {  // ---- CSR build (cnt zeroed in K_A) ----
    int e = (blk - 512) * 512 + t;
    int s = edges[2 * e], d = edges[2 * e + 1];
    int slot = atomicAdd(&cnt[d], 1);
    if (slot < CSR_CAP) csr[d * CSR_CAP + slot] = s;
    return;
  }
  // ---- FC tile: A = h1024bf (L2), B = fcwbf[tc]; 8-way K split, reduce in LDS ----
  int tr = blk >> 5, tc = blk & 31;
  const unsigned short* ap = &h1024bf[(tr * 16 + m) * 1024 + wave * 128 + quad * 8];
  const unsigned short* bp = &fcwbf[(tc * 16 + m) * 1024 + wave * 128 + quad * 8];
  float4v acc = {0.0f, 0.0f, 0.0f, 0.0f};
#pragma unroll
  for (int ks = 0; ks < 4; ks++) {
    short8 av = *(const short8*)(ap + ks * 32);
    short8 bv = *(const short8*)(bp + ks * 32);
    acc = __builtin_amdgcn_mfma_f32_16x16x32_bf16(av, bv, acc, 0, 0, 0);
  }
#pragma unroll
  for (int r = 0; r < 4; r++) red[wave * 256 + (quad * 4 + r) * 16 + m] = acc[r];
  __syncthreads();
  if (t < 256) {
    float s = 0.0f;
#pragma unroll
    for (int w = 0; w < 8; w++) s += red[w * 256 + t];
    int gr = tr * 16 + (t >> 4);
    int gc = tc * 16 + (t & 15);
    hidden[gr * 512 + gc] = fmaxf(s + fcb[gc], 0.0f);
  }
}

// ---------------- K_C: head (0..63) | enc (64..511) | dinv/xe.x (512..527) ----------------
// (512,4): ~30 VGPR class, 51.2 KB LDS -> 3 blocks/CU for the latency-bound enc GEMV.
__global__ __launch_bounds__(512, 4) void k_he(
    const float* __restrict__ hidden, const float* __restrict__ muw,
    const float* __restrict__ mub, const float* __restrict__ msgw,
    const float* __restrict__ msgb, const int* __restrict__ cnt,
    const float* __restrict__ x_msg, const int* __restrict__ action,
    float2* xe, float* dinv, float* out) {
  __shared__ float muT[10752];
  __shared__ float hrows[2048];
  int t = threadIdx.x, blk = blockIdx.x;
  int wave = t >> 6, lane = t & 63;
  if (blk >= 512) {  // dinv + xe.x = dinv*x_msg
    int i = (blk - 512) * 512 + t;
    float d = rsqrtf((float)cnt[i] + 1.0f);
    dinv[i] = d;
    xe[i].x = d * x_msg[i];
    return;
  }
  if (blk < 64) {  // head: 4 batch rows per block
    int b0 = blk * 4;
    for (int i = t; i < 10752; i += 512) {
      int a = i >> 9, k = i & 511;
      muT[k * 21 + a] = muw[i];
    }
    for (int i = t; i < 2048; i += 512) hrows[i] = hidden[b0 * 512 + i];
    __syncthreads();
    if (wave < 4) {
      int b = b0 + wave;
      float logit = -1e30f;
      if (lane < NACT) {
        float acc = mub[lane];
        const float* hr = &hrows[wave * 512];
        for (int k = 0; k < 512; k++) acc += hr[k] * muT[k * 21 + lane];
        logit = acc;
      }
      float mx = logit;
#pragma unroll
      for (int s = 32; s > 0; s >>= 1) mx = fmaxf(mx, __shfl_xor(mx, s, 64));
      float e = (lane < NACT) ? __expf(logit - mx) : 0.0f;
      float se = wsum64(e);
      float swl = wsum64(e * logit);
      float lse = mx + __logf(se);
      int act = action[b];
      if (lane == 0) {
        out[b] = (float)act;                  // action passthrough
        out[8704 + b] = lse - swl / se;       // entropy
      }
      if (lane == act) out[8448 + b] = logit - lse;  // log_prob
    }
  } else {  // enc: xe[j].y = rsqrt(cnt[j]+1) * (hidden[0].msg_w[j] + msgb[j])
    int wg = (blk - 64) * 8 + wave;  // 0..3583
    for (int j = wg; j < NA; j += 3584) {
      const float* wp = &msgw[j * 512 + lane * 8];
      float4 w0 = *(const float4*)(wp);
      float4 w1 = *(const float4*)(wp + 4);
      float4 h0 = *(const float4*)&hidden[lane * 8];
      float4 h1 = *(const float4*)&hidden[lane * 8 + 4];
      float s = w0.x * h0.x + w0.y * h0.y + w0.z * h0.z + w0.w * h0.w +
                w1.x * h1.x + w1.y * h1.y + w1.z * h1.z + w1.w * h1.w;
      s = wsum64(s);
      if (lane == 0) xe[j].y = rsqrtf((float)cnt[j] + 1.0f) * (s + msgb[j]);
    }
  }
}

// ---------------- K_D: GCN1 gather (2 rows per wave, 512 blocks; packed xe loads) ----------------
__global__ __launch_bounds__(512, 4) void k_g1(
    const int* __restrict__ cnt, const int* __restrict__ csr,
    const float* __restrict__ dinv, const float2* __restrict__ xe,
    const float* __restrict__ g1w, const float* __restrict__ g1b, float* gbuf2) {
  int t = threadIdx.x, blk = blockIdx.x;
  int wave = t >> 6, lane = t & 63;
  int wg = blk * 8 + wave;  // 0..4095
#pragma unroll
  for (int rr = 0; rr < 2; rr++) {
    int i = wg * 2 + rr;
    int ci = min(cnt[i], CSR_CAP);
    float di = dinv[i];
    float a0 = 0.0f, a1 = 0.0f;
    for (int e = lane; e < ci; e += 64) {
      int s = csr[i * CSR_CAP + e];
      float2 v = xe[s];  // one 8B load instead of two 4B random loads
      a0 += v.x;
      a1 += v.y;
    }
    float2 vi = xe[i];
    float f0 = (wsum64(a0) + vi.x) * di;
    float f1 = (wsum64(a1) + vi.y) * di;
    if (lane < 16) {
      float gv = fmaxf(f0 * g1w[lane] + f1 * g1w[16 + lane] + g1b[lane], 0.0f);
      gbuf2[i * 16 + lane] = di * gv;
    }
  }
}

// ---------------- K_E: GCN2 gather + MFMA scores + sum-exp (16 rows/block, 512 blocks) ----------------
__global__ __launch_bounds__(512, 4) void k_msg(
    const int* __restrict__ cnt, const int* __restrict__ csr,
    const float* __restrict__ dinv, const float* __restrict__ gbuf2,
    const float* __restrict__ wsf, const unsigned short* __restrict__ w2t,
    const float* __restrict__ g2b, float* out) {
  __shared__ __align__(16) unsigned short vbf[256];
  __shared__ float vf[256];
  __shared__ float pl[2048];
  __shared__ float sl[128];
  __shared__ float wsfs[17];
  int t = threadIdx.x, blk = blockIdx.x;
  int wave = t >> 6, lane = t & 63;
  int rowbase = blk * 16;
  if (t < 17) wsfs[t] = wsf[t];
  {  // gather 16 V rows
    int eq = lane >> 4, c = lane & 15;
#pragma unroll
    for (int rr = 0; rr < 2; rr++) {
      int il = wave * 2 + rr;
      int i = rowbase + il;
      int ci = min(cnt[i], CSR_CAP);
      float di = dinv[i];
      float acc = (eq == 0) ? gbuf2[i * 16 + c] : 0.0f;
      for (int e = eq; e < ci; e += 4) {
        int s = csr[i * CSR_CAP + e];
        acc += gbuf2[s * 16 + c];
      }
      acc *= di;
      acc += __shfl_xor(acc, 16, 64);
      acc += __shfl_xor(acc, 32, 64);
      if (eq == 0) {
        vf[il * 16 + c] = acc;
        vbf[il * 16 + c] = f2bf(acc * LOG2E);
      }
    }
  }
  __syncthreads();
  float myMean = 0.0f;
  if (t < 16) {
    float dot = 0.0f;
#pragma unroll
    for (int c = 0; c < 16; c++) dot += vf[t * 16 + c] * wsfs[c];
    myMean = (dot + wsfs[16]) * (1.0f / 8192.0f);
  }
  {  // scores via MFMA + exp2
    int quad = lane >> 4, n = lane & 15;
    int k8 = quad * 8;
    short8 za = {0, 0, 0, 0, 0, 0, 0, 0};
    short8 a1 = za;
    if (quad < 2) a1 = *(const short8*)&vbf[n * 16 + k8];
    float sacc[4];
#pragma unroll
    for (int q = 0; q < 4; q++) sacc[q] = 0.0f;
    int colb = wave * 1024 + n;
    for (int tp = 0; tp < 64; tp += 2) {
      int col1 = colb + tp * 16;
      int col2 = col1 + 16;
      short8 b1 = za, b2 = za;
      if (quad < 2) {
        b1 = *(const short8*)&w2t[col1 * 16 + k8];
        b2 = *(const short8*)&w2t[col2 * 16 + k8];
      }
      float bb1 = g2b[col1] * LOG2E, bb2 = g2b[col2] * LOG2E;
      float4v c1 = {bb1, bb1, bb1, bb1};
      float4v c2 = {bb2, bb2, bb2, bb2};
      float4v s11 = __builtin_amdgcn_mfma_f32_16x16x32_bf16(a1, b1, c1, 0, 0, 0);
      float4v s12 = __builtin_amdgcn_mfma_f32_16x16x32_bf16(a1, b2, c2, 0, 0, 0);
#pragma unroll
      for (int r = 0; r < 4; r++) sacc[r] += EXP2F(s11[r]) + EXP2F(s12[r]);
    }
#pragma unroll
    for (int q = 0; q < 4; q++) {
      int rl = quad * 4 + q;
      pl[rl * 128 + wave * 16 + n] = sacc[q];
    }
  }
  __syncthreads();
  if (t < 128) {
    int r = t >> 3, seg = t & 7;
    int base = r * 128 + seg * 16;
    float ll = 0.0f;
#pragma unroll
    for (int i = 0; i < 16; i++) ll += pl[base + i];
    sl[r * 8 + seg] = ll;
  }
  __syncthreads();
  if (t < 16) {
    float ll = 0.0f;
#pragma unroll
    for (int i = 0; i < 8; i++) ll += sl[t * 8 + i];
    out[256 + rowbase + t] = myMean - __logf(ll);
  }
}

extern "C" void kernel_launch(void* const* d_in, const int* in_sizes, int n_in,
                              void* d_out, int out_size, void* d_ws, size_t ws_size,
                              hipStream_t stream) {
  const float* x     = (const float*)d_in[0];
  const float* x_msg = (const float*)d_in[1];
  const int*   edges = (const int*)d_in[2];
  const int*   action= (const int*)d_in[3];
  const float* c1w   = (const float*)d_in[4];
  const float* c1bb  = (const float*)d_in[5];
  const float* c2w   = (const float*)d_in[6];
  const float* c2b   = (const float*)d_in[7];
  const float* fcw   = (const float*)d_in[8];
  const float* fcb   = (const float*)d_in[9];
  const float* muw   = (const float*)d_in[10];
  const float* mub   = (const float*)d_in[11];
  const float* msgw  = (const float*)d_in[12];
  const float* msgb  = (const float*)d_in[13];
  const float* g1w   = (const float*)d_in[14];
  const float* g1b   = (const float*)d_in[15];
  const float* g2w   = (const float*)d_in[16];
  const float* g2b   = (const float*)d_in[17];
  float* out = (float*)d_out;  // reference outputs are fp32

  float* ws     = (float*)d_ws;
  unsigned short* h1024bf = (unsigned short*)ws;            // 262144 bf16 = 131072 f
  unsigned short* fcwbf   = (unsigned short*)(ws + 131072); // 524288 bf16 = 262144 f
  float* hidden = ws + 393216;           // 131072
  float2* xe    = (float2*)(ws + 524288);  // 8192 float2 = 16384 f -> ends 540672
  float* dinv   = ws + 540672;           // 8192 -> ends 548864
  float* gbuf2  = ws + 548864;           // 131072
  float* wpart  = ws + 679936;           // 8704
  unsigned short* w2t = (unsigned short*)(ws + 688640);     // 131072 bf16 = 65536 f
  int*   cnt    = (int*)(ws + 754176);   // 8192 ints
  int*   csr    = (int*)(ws + 762368);   // 1048576 ints -> ends at float-offset 1810944
  float* wsf    = ws + 1810944;          // 17

  k_ip <<<784, 512, 0, stream>>>(x, c1w, c1bb, c2w, c2b, fcw, g2w, g2b,
                                 h1024bf, cnt, fcwbf, w2t, wpart);
  k_cf <<<1025, 512, 0, stream>>>(edges, cnt, csr, h1024bf, fcwbf, fcb, wpart,
                                  hidden, wsf);
  k_he <<<528, 512, 0, stream>>>(hidden, muw, mub, msgw, msgb, cnt, x_msg,
                                 action, xe, dinv, out);
  k_g1 <<<512, 512, 0, stream>>>(cnt, csr, dinv, xe, g1w, g1b, gbuf2);
  k_msg<<<512, 512, 0, stream>>>(cnt, csr, dinv, gbuf2, wsf, w2t, g2b, out);
}